// Round 2
// baseline (967.624 us; speedup 1.0000x reference)
//
#include <hip/hip_runtime.h>

#define D_MODEL 1024
#define LSEQ    8192
#define NC      8192            // complex FFT size = (2*L)/2
#define TWO_PI_OVER_N 3.8349519697141029e-4f   // 2*pi/16384

// Double-XOR swizzle on LDS float2 index: keeps unit-stride wave patterns
// conflict-free (permutes within 16-element blocks) and caps the scattered
// chunk / h=16 / megapass patterns at 4-way.
__device__ __forceinline__ int sw(int e) { return e ^ ((e >> 4) & 15) ^ ((e >> 9) & 15); }
// base-8 3-digit reverse of a 9-bit chunk id
__device__ __forceinline__ int sig3(int c) { return ((c & 7) << 6) | (c & 56) | (c >> 6); }

__device__ __forceinline__ float2 cadd(float2 a, float2 b){ return make_float2(a.x+b.x, a.y+b.y); }
__device__ __forceinline__ float2 csub(float2 a, float2 b){ return make_float2(a.x-b.x, a.y-b.y); }
__device__ __forceinline__ float2 cmul(float2 a, float2 b){ return make_float2(a.x*b.x-a.y*b.y, a.x*b.y+a.y*b.x); }
template<int S> __device__ __forceinline__ float2 rot(float2 z){  // S=-1: -i*z ; S=+1: +i*z
    return (S < 0) ? make_float2(z.y, -z.x) : make_float2(-z.y, z.x);
}

// 8-point DFT, natural-order in/out. S=-1 forward (e^{-i}), S=+1 unscaled inverse.
template<int S>
__device__ __forceinline__ void dft8(float2 v[8]) {
    const float c = 0.70710678118654752f;
    float2 a0=cadd(v[0],v[4]), m0=csub(v[0],v[4]);
    float2 a1=cadd(v[1],v[5]), m1=csub(v[1],v[5]);
    float2 a2=cadd(v[2],v[6]), m2=csub(v[2],v[6]);
    float2 a3=cadd(v[3],v[7]), m3=csub(v[3],v[7]);
    m1 = cmul(m1, make_float2(c, S*c));
    m2 = rot<S>(m2);
    m3 = cmul(m3, make_float2(-c, S*c));
    float2 b0=cadd(a0,a2), b2=csub(a0,a2);
    float2 b1=cadd(a1,a3), b3=rot<S>(csub(a1,a3));
    float2 e0=cadd(m0,m2), e2=csub(m0,m2);
    float2 e1=cadd(m1,m3), e3=rot<S>(csub(m1,m3));
    v[0]=cadd(b0,b1); v[4]=csub(b0,b1);
    v[2]=cadd(b2,b3); v[6]=csub(b2,b3);
    v[1]=cadd(e0,e1); v[5]=csub(e0,e1);
    v[3]=cadd(e2,e3); v[7]=csub(e2,e3);
}

// 16-point DFT, natural-order in/out (two radix-4 stages, constant twiddles).
template<int S>
__device__ __forceinline__ void dft16(float2 v[16]) {
    const float c  = 0.70710678118654752f;
    const float cp = 0.92387953251128676f;   // cos(pi/8)
    const float spp= 0.38268343236508977f;   // sin(pi/8)
    const float2 w1 = make_float2(cp,  S*spp);
    const float2 w2 = make_float2(c,   S*c);
    const float2 w3 = make_float2(spp, S*cp);
    const float2 w6 = make_float2(-c,  S*c);
    const float2 w9 = make_float2(-cp, -S*spp);
    float2 y[16];
    #pragma unroll
    for (int n=0;n<4;++n) {
        float2 s02=cadd(v[n],v[n+8]),  d02=csub(v[n],v[n+8]);
        float2 s13=cadd(v[n+4],v[n+12]), d13=csub(v[n+4],v[n+12]);
        float2 rd = rot<S>(d13);
        float2 F0=cadd(s02,s13), F2=csub(s02,s13);
        float2 F1=cadd(d02,rd),  F3=csub(d02,rd);
        y[n] = F0;
        if (n==0)      { y[4]=F1;            y[8]=F2;            y[12]=F3; }
        else if (n==1) { y[5]=cmul(F1,w1);   y[9]=cmul(F2,w2);   y[13]=cmul(F3,w3); }
        else if (n==2) { y[6]=cmul(F1,w2);   y[10]=rot<S>(F2);   y[14]=cmul(F3,w6); }
        else           { y[7]=cmul(F1,w3);   y[11]=cmul(F2,w6);  y[15]=cmul(F3,w9); }
    }
    #pragma unroll
    for (int r1=0;r1<4;++r1) {
        float2 q0=y[4*r1], q1=y[4*r1+1], q2=y[4*r1+2], q3=y[4*r1+3];
        float2 s02=cadd(q0,q2), d02=csub(q0,q2);
        float2 s13=cadd(q1,q3), d13=csub(q1,q3);
        float2 rd = rot<S>(d13);
        v[r1]    = cadd(s02,s13);
        v[4+r1]  = cadd(d02,rd);
        v[8+r1]  = csub(s02,s13);
        v[12+r1] = csub(d02,rd);
    }
}

// Radix-8 DIF pass, span H. FUSED=1: read legs from global (j<4), zero-pad j>=4.
template<int H, int FUSED>
__device__ __forceinline__ void r8_fwd(float2* s, const float2* gsrc, int tid) {
    const float ANG = -6.2831853071795865f / (8.0f * (float)H);
    #pragma unroll
    for (int t=0;t<4;++t) {
        int bf  = tid + t*256;
        int pos = bf & (H-1);
        int base = (bf - pos)*8 + pos;     // (bf/H)*8H + pos
        float2 v[8];
        if (FUSED) {
            #pragma unroll
            for (int j=0;j<4;++j) v[j] = gsrc[pos + j*1024];
            #pragma unroll
            for (int j=4;j<8;++j) v[j] = make_float2(0.f,0.f);
        } else {
            #pragma unroll
            for (int j=0;j<8;++j) v[j] = s[sw(base + j*H)];
        }
        dft8<-1>(v);
        float sn, cs; __sincosf(ANG * (float)pos, &sn, &cs);
        float2 w = make_float2(cs, sn), wr = w;
        v[1] = cmul(v[1], wr);
        #pragma unroll
        for (int r=2;r<8;++r) { wr = cmul(wr, w); v[r] = cmul(v[r], wr); }
        #pragma unroll
        for (int r=0;r<8;++r) s[sw(base + r*H)] = v[r];
    }
}

// Radix-8 DIT inverse pass, span H. EPI=1 (H=1024 only): fuse epilogue
// out[e] = y[e] + x[e]*Dd for e<4096 (second half discarded), skip LDS write.
template<int H, int EPI>
__device__ __forceinline__ void r8_inv(float2* s, int tid, const float2* xg, float2* og, float Dd) {
    const float ANG = 6.2831853071795865f / (8.0f * (float)H);
    #pragma unroll
    for (int t=0;t<4;++t) {
        int bf  = tid + t*256;
        int pos = bf & (H-1);
        int base = (bf - pos)*8 + pos;
        float2 xr8[4];
        if (EPI) {
            #pragma unroll
            for (int j=0;j<4;++j) xr8[j] = xg[pos + j*1024];
        }
        float2 v[8];
        #pragma unroll
        for (int r=0;r<8;++r) v[r] = s[sw(base + r*H)];
        float sn, cs; __sincosf(ANG * (float)pos, &sn, &cs);
        float2 w = make_float2(cs, sn), wr = w;
        v[1] = cmul(v[1], wr);
        #pragma unroll
        for (int r=2;r<8;++r) { wr = cmul(wr, w); v[r] = cmul(v[r], wr); }
        dft8<1>(v);
        if (EPI) {
            #pragma unroll
            for (int j=0;j<4;++j) {
                og[pos + j*1024] = make_float2(v[j].x + xr8[j].x*Dd, v[j].y + xr8[j].y*Dd);
            }
        } else {
            #pragma unroll
            for (int j=0;j<8;++j) s[sw(base + j*H)] = v[j];
        }
    }
}

// Packed-real spectrum pair math (validated in round 1).
// cs,sn = sincos(2*pi*k/16384); forward kernel w = (cs,-sn).
__device__ __forceinline__ void filt_pair(float2 Ck, float2 Cm, float cs, float sn,
                                          float2& Kk, float2& Km) {
    const float hN = 0.5f / 16384.0f;
    float2 E  = make_float2(Ck.x + Cm.x, Ck.y - Cm.y);
    float2 O  = make_float2(Ck.x - Cm.x, Ck.y + Cm.y);
    float2 WO = make_float2(O.x*cs + O.y*sn, -O.x*sn + O.y*cs);
    float2 T  = make_float2(-WO.y, WO.x);
    Kk = make_float2((E.x - T.x)*hN,  (E.y - T.y)*hN);
    Km = make_float2((E.x + T.x)*hN, -(E.y + T.y)*hN);
}
__device__ __forceinline__ void conv_pair(float2 Ck, float2 Cm, float2 Kk, float2 Km,
                                          float cs, float sn, float2& Zk, float2& Zm) {
    float2 E  = make_float2(Ck.x + Cm.x, Ck.y - Cm.y);
    float2 O  = make_float2(Ck.x - Cm.x, Ck.y + Cm.y);
    float2 WO = make_float2(O.x*cs + O.y*sn, -O.x*sn + O.y*cs);
    float2 T  = make_float2(-WO.y, WO.x);
    float2 Uk = make_float2(0.5f*(E.x - T.x),  0.5f*(E.y - T.y));
    float2 Um = make_float2(0.5f*(E.x + T.x), -0.5f*(E.y + T.y));
    float2 Yk = cmul(Uk, Kk);
    float2 Ym = cmul(Um, Km);
    float2 P  = make_float2(Yk.x + Ym.x, Yk.y - Ym.y);
    float2 Q  = make_float2(Yk.x - Ym.x, Yk.y + Ym.y);
    float2 CQ = make_float2(Q.x*cs - Q.y*sn, Q.x*sn + Q.y*cs);
    float2 T2 = make_float2(-CQ.y, CQ.x);
    Zk = make_float2(P.x + T2.x, P.y + T2.y);
    Zm = make_float2(P.x - T2.x, -(P.y - T2.y));
}

// ---------------------------------------------------------------------------
// Kernel 1: implicit-filter MLP + out-projection + exponential modulation.
// grid (128,4): 64 positions x 256 channels per block.
// ---------------------------------------------------------------------------
__global__ void __launch_bounds__(256,2) hyena_filter_k(
    const float* __restrict__ W1, const float* __restrict__ b1,
    const float* __restrict__ freq,
    const float* __restrict__ W2, const float* __restrict__ b2,
    const float* __restrict__ W3, const float* __restrict__ b3,
    const float* __restrict__ Wout,
    float* __restrict__ kout)
{
    __shared__ float zbuf[64][35];
    __shared__ float abuf[64][65];
    __shared__ float bbuf[64][65];
    __shared__ float wbuf[4096];

    const int tid = threadIdx.x;
    const int pbase = blockIdx.x * 64;

    for (int i = tid; i < 33*64; i += 256) wbuf[i] = W1[i];
    for (int idx = tid; idx < 64*33; idx += 256) {
        int p = idx & 63, e = idx >> 6;
        int gp = pbase + p;
        float w = 7.6699039394282907e-4f * (float)gp;   // 2*pi*gp/8192
        float val;
        if (e == 0)       val = (float)gp / 8191.0f;
        else if (e < 17)  val =  cosf((1.0e-4f + (float)(e-1 ) * ((15.0f-1.0e-4f)/15.0f)) * w);
        else              val = -sinf((1.0e-4f + (float)(e-17) * ((15.0f-1.0e-4f)/15.0f)) * w);
        zbuf[p][e] = val;
    }
    __syncthreads();

    const int p = tid & 63;
    const int g = tid >> 6;

    for (int oo = 0; oo < 16; ++oo) {
        int o = g*16 + oo;
        float acc = b1[o];
        #pragma unroll
        for (int e = 0; e < 33; ++e) acc += zbuf[p][e] * wbuf[e*64 + o];
        abuf[p][o] = __sinf(freq[o] * acc);
    }
    __syncthreads();
    for (int i = tid; i < 4096; i += 256) wbuf[i] = W2[i];
    __syncthreads();
    for (int oo = 0; oo < 16; ++oo) {
        int o = g*16 + oo;
        float acc = b2[o];
        #pragma unroll
        for (int e = 0; e < 64; ++e) acc += abuf[p][e] * wbuf[e*64 + o];
        bbuf[p][o] = __sinf(freq[o] * acc);
    }
    __syncthreads();
    for (int i = tid; i < 4096; i += 256) wbuf[i] = W3[i];
    __syncthreads();
    for (int oo = 0; oo < 16; ++oo) {
        int o = g*16 + oo;
        float acc = b3[o];
        #pragma unroll
        for (int e = 0; e < 64; ++e) acc += bbuf[p][e] * wbuf[e*64 + o];
        abuf[p][o] = __sinf(freq[o] * acc);
    }
    __syncthreads();

    // out-projection: channels-in-lanes, Wout column in registers.
    const int dd = blockIdx.y*256 + tid;
    float wreg[64];
    #pragma unroll
    for (int o = 0; o < 64; ++o) wreg[o] = Wout[o*1024 + dd];
    const float mind  = -3.0701134573253940f;
    const float dstep = -0.012004353694331942f;
    const float delta = fabsf(mind + dstep * (float)dd);
    float* orow = kout + (size_t)dd * LSEQ + pbase;
    for (int pp = 0; pp < 64; ++pp) {
        float a0=0.f, a1=0.f, a2=0.f, a3=0.f;
        #pragma unroll
        for (int o = 0; o < 64; o += 4) {
            a0 += abuf[pp][o  ] * wreg[o  ];
            a1 += abuf[pp][o+1] * wreg[o+1];
            a2 += abuf[pp][o+2] * wreg[o+2];
            a3 += abuf[pp][o+3] * wreg[o+3];
        }
        float t = (float)(pbase + pp) / 8191.0f;
        orow[pp] = (a0+a1+a2+a3) * __expf(-t * delta);
    }
}

// ---------------------------------------------------------------------------
// Kernel 2: per-channel FFT causal convolution + skip. One block per channel.
// Radix-8^3 x 16 FFT; filter spectrum in registers; fused global I/O passes.
// ---------------------------------------------------------------------------
__global__ void __launch_bounds__(256,2) hyena_conv_k(
    const float* __restrict__ x, const float* kin,
    const float* __restrict__ Dvec, float* out)
{
    __shared__ float2 s[NC];                 // 64 KB
    const int tid = threadIdx.x;
    const int d = blockIdx.x;
    const float Dd = Dvec[d];
    const float invN = 1.0f / 16384.0f;

    // chunk pairing: thread tid owns chunks {tid, 512-tid}; thread 0 owns {0, 256}.
    const int cA = (tid == 0) ? 0   : tid;
    const int cB = (tid == 0) ? 256 : 512 - tid;
    const int baseA = 16 * sig3(cA);
    const int baseB = 16 * sig3(cB);

    // ---- filter FFT (passes 1-3) ----
    const float2* kb = (const float2*)kin + (size_t)d * 4096;
    r8_fwd<1024,1>(s, kb, tid);
    __syncthreads();
    r8_fwd<128,0>(s, nullptr, tid);
    __syncthreads();
    r8_fwd<16,0>(s, nullptr, tid);
    __syncthreads();

    // ---- K extraction: chunk dft16 in registers -> spectrum multipliers ----
    float2 Ka[16], Kb[16];
    {
        float2 Ua[16], Ub[16];
        #pragma unroll
        for (int i = 0; i < 16; ++i) { Ua[i] = s[sw(baseA+i)]; Ub[i] = s[sw(baseB+i)]; }
        dft16<-1>(Ua); dft16<-1>(Ub);
        if (tid != 0) {
            #pragma unroll
            for (int v = 0; v < 16; ++v) {
                int k = tid + 512*v;
                float sn, cs; __sincosf(TWO_PI_OVER_N*(float)k, &sn, &cs);
                filt_pair(Ua[v], Ub[15-v], cs, sn, Ka[v], Kb[v]);
            }
        } else {
            Ka[0] = make_float2((Ua[0].x+Ua[0].y)*invN, (Ua[0].x-Ua[0].y)*invN); // K[0],K[8192]
            Kb[0] = make_float2(Ua[8].x*invN, -Ua[8].y*invN);                    // conj(C[4096])/N
            #pragma unroll
            for (int v = 1; v < 8; ++v) {
                int k = 512*v;
                float sn, cs; __sincosf(TWO_PI_OVER_N*(float)k, &sn, &cs);
                filt_pair(Ua[v], Ua[16-v], cs, sn, Ka[v], Kb[v]);
            }
            #pragma unroll
            for (int j = 0; j < 8; ++j) {
                int k = 256 + 512*j;
                float sn, cs; __sincosf(TWO_PI_OVER_N*(float)k, &sn, &cs);
                filt_pair(Ub[j], Ub[15-j], cs, sn, Ka[8+j], Kb[8+j]);
            }
        }
    }

    // ---- per-batch conv ----
    for (int b = 0; b < 2; ++b) {
        __syncthreads();
        const float2* xv = (const float2*)x + ((size_t)b*D_MODEL + d) * 4096;
        float2* ov = (float2*)out + ((size_t)b*D_MODEL + d) * 4096;

        r8_fwd<1024,1>(s, xv, tid);
        __syncthreads();
        r8_fwd<128,0>(s, nullptr, tid);
        __syncthreads();
        r8_fwd<16,0>(s, nullptr, tid);
        __syncthreads();

        // megapass: dft16 -> unpack*K -> repack -> idft16, all in registers
        {
            float2 Ua[16], Ub[16];
            #pragma unroll
            for (int i = 0; i < 16; ++i) { Ua[i] = s[sw(baseA+i)]; Ub[i] = s[sw(baseB+i)]; }
            dft16<-1>(Ua); dft16<-1>(Ub);
            if (tid != 0) {
                #pragma unroll
                for (int v = 0; v < 16; ++v) {
                    int k = tid + 512*v;
                    float sn, cs; __sincosf(TWO_PI_OVER_N*(float)k, &sn, &cs);
                    float2 Zk, Zm;
                    conv_pair(Ua[v], Ub[15-v], Ka[v], Kb[v], cs, sn, Zk, Zm);
                    Ua[v] = Zk; Ub[15-v] = Zm;
                }
            } else {
                float U0 = Ua[0].x + Ua[0].y, UNq = Ua[0].x - Ua[0].y;
                float Y0 = U0 * Ka[0].x, YN = UNq * Ka[0].y;
                float2 z0 = make_float2(Y0 + YN, Y0 - YN);
                float2 Uq = make_float2(Ua[8].x, -Ua[8].y);
                float2 Yq = cmul(Uq, Kb[0]);
                float2 z8 = make_float2(2.f*Yq.x, -2.f*Yq.y);
                #pragma unroll
                for (int v = 1; v < 8; ++v) {
                    int k = 512*v;
                    float sn, cs; __sincosf(TWO_PI_OVER_N*(float)k, &sn, &cs);
                    float2 Zk, Zm;
                    conv_pair(Ua[v], Ua[16-v], Ka[v], Kb[v], cs, sn, Zk, Zm);
                    Ua[v] = Zk; Ua[16-v] = Zm;
                }
                Ua[0] = z0; Ua[8] = z8;
                #pragma unroll
                for (int j = 0; j < 8; ++j) {
                    int k = 256 + 512*j;
                    float sn, cs; __sincosf(TWO_PI_OVER_N*(float)k, &sn, &cs);
                    float2 Zk, Zm;
                    conv_pair(Ub[j], Ub[15-j], Ka[8+j], Kb[8+j], cs, sn, Zk, Zm);
                    Ub[j] = Zk; Ub[15-j] = Zm;
                }
            }
            dft16<1>(Ua); dft16<1>(Ub);
            #pragma unroll
            for (int i = 0; i < 16; ++i) { s[sw(baseA+i)] = Ua[i]; s[sw(baseB+i)] = Ub[i]; }
        }
        __syncthreads();
        r8_inv<16,0>(s, tid, nullptr, nullptr, 0.f);
        __syncthreads();
        r8_inv<128,0>(s, tid, nullptr, nullptr, 0.f);
        __syncthreads();
        r8_inv<1024,1>(s, tid, xv, ov, Dd);   // fused epilogue: y + x*D -> out
    }
}

extern "C" void kernel_launch(void* const* d_in, const int* in_sizes, int n_in,
                              void* d_out, int out_size, void* d_ws, size_t ws_size,
                              hipStream_t stream) {
    (void)in_sizes; (void)n_in; (void)out_size; (void)d_ws; (void)ws_size;
    const float* x    = (const float*)d_in[0];
    const float* W1   = (const float*)d_in[2];
    const float* b1   = (const float*)d_in[3];
    const float* freq = (const float*)d_in[4];
    const float* W2   = (const float*)d_in[5];
    const float* b2   = (const float*)d_in[6];
    const float* W3   = (const float*)d_in[7];
    const float* b3   = (const float*)d_in[8];
    const float* Wout = (const float*)d_in[9];
    const float* Dv   = (const float*)d_in[10];
    float* out = (float*)d_out;

    // Time-domain filter k[1024][8192] lives in the b=0 half of d_out:
    // conv block d is the sole reader of k[d] and sole later writer of out[0][d].
    float* kbuf = out;

    hipLaunchKernelGGL(hyena_filter_k, dim3(128, 4), dim3(256), 0, stream,
                       W1, b1, freq, W2, b2, W3, b3, Wout, kbuf);
    hipLaunchKernelGGL(hyena_conv_k, dim3(1024), dim3(256), 0, stream,
                       x, kbuf, Dv, out);
}

// Round 3
// 947.153 us; speedup vs baseline: 1.0216x; 1.0216x over previous
//
#include <hip/hip_runtime.h>

#define D_MODEL 1024
#define LSEQ    8192
#define NC      8192            // complex FFT size = (2*L)/2
#define TWO_PI_OVER_N 3.8349519697141029e-4f   // 2*pi/16384

// Double-XOR swizzle on LDS float2 index: keeps unit-stride wave patterns
// conflict-free and caps scattered chunk/pairing patterns at ~4-way.
__device__ __forceinline__ int sw(int e) { return e ^ ((e >> 4) & 15) ^ ((e >> 9) & 15); }
// base-8 3-digit reverse of a 9-bit chunk id
__device__ __forceinline__ int sig3(int c) { return ((c & 7) << 6) | (c & 56) | (c >> 6); }

__device__ __forceinline__ float2 cadd(float2 a, float2 b){ return make_float2(a.x+b.x, a.y+b.y); }
__device__ __forceinline__ float2 csub(float2 a, float2 b){ return make_float2(a.x-b.x, a.y-b.y); }
__device__ __forceinline__ float2 cmul(float2 a, float2 b){ return make_float2(a.x*b.x-a.y*b.y, a.x*b.y+a.y*b.x); }
template<int S> __device__ __forceinline__ float2 rot(float2 z){  // S=-1: -i*z ; S=+1: +i*z
    return (S < 0) ? make_float2(z.y, -z.x) : make_float2(-z.y, z.x);
}

// 8-point DFT, natural-order in/out. S=-1 forward, S=+1 unscaled inverse.
template<int S>
__device__ __forceinline__ void dft8(float2 v[8]) {
    const float c = 0.70710678118654752f;
    float2 a0=cadd(v[0],v[4]), m0=csub(v[0],v[4]);
    float2 a1=cadd(v[1],v[5]), m1=csub(v[1],v[5]);
    float2 a2=cadd(v[2],v[6]), m2=csub(v[2],v[6]);
    float2 a3=cadd(v[3],v[7]), m3=csub(v[3],v[7]);
    m1 = cmul(m1, make_float2(c, S*c));
    m2 = rot<S>(m2);
    m3 = cmul(m3, make_float2(-c, S*c));
    float2 b0=cadd(a0,a2), b2=csub(a0,a2);
    float2 b1=cadd(a1,a3), b3=rot<S>(csub(a1,a3));
    float2 e0=cadd(m0,m2), e2=csub(m0,m2);
    float2 e1=cadd(m1,m3), e3=rot<S>(csub(m1,m3));
    v[0]=cadd(b0,b1); v[4]=csub(b0,b1);
    v[2]=cadd(b2,b3); v[6]=csub(b2,b3);
    v[1]=cadd(e0,e1); v[5]=csub(e0,e1);
    v[3]=cadd(e2,e3); v[7]=csub(e2,e3);
}

// 16-point DFT, natural-order in/out (two radix-4 stages, constant twiddles).
template<int S>
__device__ __forceinline__ void dft16(float2 v[16]) {
    const float c  = 0.70710678118654752f;
    const float cp = 0.92387953251128676f;   // cos(pi/8)
    const float spp= 0.38268343236508977f;   // sin(pi/8)
    const float2 w1 = make_float2(cp,  S*spp);
    const float2 w2 = make_float2(c,   S*c);
    const float2 w3 = make_float2(spp, S*cp);
    const float2 w6 = make_float2(-c,  S*c);
    const float2 w9 = make_float2(-cp, -S*spp);
    float2 y[16];
    #pragma unroll
    for (int n=0;n<4;++n) {
        float2 s02=cadd(v[n],v[n+8]),  d02=csub(v[n],v[n+8]);
        float2 s13=cadd(v[n+4],v[n+12]), d13=csub(v[n+4],v[n+12]);
        float2 rd = rot<S>(d13);
        float2 F0=cadd(s02,s13), F2=csub(s02,s13);
        float2 F1=cadd(d02,rd),  F3=csub(d02,rd);
        y[n] = F0;
        if (n==0)      { y[4]=F1;            y[8]=F2;            y[12]=F3; }
        else if (n==1) { y[5]=cmul(F1,w1);   y[9]=cmul(F2,w2);   y[13]=cmul(F3,w3); }
        else if (n==2) { y[6]=cmul(F1,w2);   y[10]=rot<S>(F2);   y[14]=cmul(F3,w6); }
        else           { y[7]=cmul(F1,w3);   y[11]=cmul(F2,w6);  y[15]=cmul(F3,w9); }
    }
    #pragma unroll
    for (int r1=0;r1<4;++r1) {
        float2 q0=y[4*r1], q1=y[4*r1+1], q2=y[4*r1+2], q3=y[4*r1+3];
        float2 s02=cadd(q0,q2), d02=csub(q0,q2);
        float2 s13=cadd(q1,q3), d13=csub(q1,q3);
        float2 rd = rot<S>(d13);
        v[r1]    = cadd(s02,s13);
        v[4+r1]  = cadd(d02,rd);
        v[8+r1]  = csub(s02,s13);
        v[12+r1] = csub(d02,rd);
    }
}

// Radix-8 DIF pass, span H. FUSED=1: read legs from global (j<4), zero-pad j>=4.
template<int H, int FUSED>
__device__ __forceinline__ void r8_fwd(float2* s, const float2* gsrc, int tid) {
    const float ANG = -6.2831853071795865f / (8.0f * (float)H);
    #pragma unroll
    for (int t=0;t<4;++t) {
        int bf  = tid + t*256;
        int pos = bf & (H-1);
        int base = (bf - pos)*8 + pos;     // (bf/H)*8H + pos
        float2 v[8];
        if (FUSED) {
            #pragma unroll
            for (int j=0;j<4;++j) v[j] = gsrc[pos + j*1024];
            #pragma unroll
            for (int j=4;j<8;++j) v[j] = make_float2(0.f,0.f);
        } else {
            #pragma unroll
            for (int j=0;j<8;++j) v[j] = s[sw(base + j*H)];
        }
        dft8<-1>(v);
        float sn, cs; __sincosf(ANG * (float)pos, &sn, &cs);
        float2 w = make_float2(cs, sn), wr = w;
        v[1] = cmul(v[1], wr);
        #pragma unroll
        for (int r=2;r<8;++r) { wr = cmul(wr, w); v[r] = cmul(v[r], wr); }
        #pragma unroll
        for (int r=0;r<8;++r) s[sw(base + r*H)] = v[r];
    }
}

// Radix-8 DIT inverse pass, span H. EPI=1 (H=1024 only): fused epilogue
// out[e] = y[e] + x[e]*Dd for e<4096 (second half discarded), skip LDS write.
template<int H, int EPI>
__device__ __forceinline__ void r8_inv(float2* s, int tid, const float2* xg, float2* og, float Dd) {
    const float ANG = 6.2831853071795865f / (8.0f * (float)H);
    #pragma unroll
    for (int t=0;t<4;++t) {
        int bf  = tid + t*256;
        int pos = bf & (H-1);
        int base = (bf - pos)*8 + pos;
        float2 xr8[4];
        if (EPI) {
            #pragma unroll
            for (int j=0;j<4;++j) xr8[j] = xg[pos + j*1024];
        }
        float2 v[8];
        #pragma unroll
        for (int r=0;r<8;++r) v[r] = s[sw(base + r*H)];
        float sn, cs; __sincosf(ANG * (float)pos, &sn, &cs);
        float2 w = make_float2(cs, sn), wr = w;
        v[1] = cmul(v[1], wr);
        #pragma unroll
        for (int r=2;r<8;++r) { wr = cmul(wr, w); v[r] = cmul(v[r], wr); }
        dft8<1>(v);
        if (EPI) {
            #pragma unroll
            for (int j=0;j<4;++j) {
                og[pos + j*1024] = make_float2(v[j].x + xr8[j].x*Dd, v[j].y + xr8[j].y*Dd);
            }
        } else {
            #pragma unroll
            for (int j=0;j<8;++j) s[sw(base + j*H)] = v[j];
        }
    }
}

// Packed-real spectrum pair math (verified rounds 1-2).
__device__ __forceinline__ void filt_pair(float2 Ck, float2 Cm, float cs, float sn,
                                          float2& Kk, float2& Km) {
    const float hN = 0.5f / 16384.0f;
    float2 E  = make_float2(Ck.x + Cm.x, Ck.y - Cm.y);
    float2 O  = make_float2(Ck.x - Cm.x, Ck.y + Cm.y);
    float2 WO = make_float2(O.x*cs + O.y*sn, -O.x*sn + O.y*cs);
    float2 T  = make_float2(-WO.y, WO.x);
    Kk = make_float2((E.x - T.x)*hN,  (E.y - T.y)*hN);
    Km = make_float2((E.x + T.x)*hN, -(E.y + T.y)*hN);
}
__device__ __forceinline__ void conv_pair(float2 Ck, float2 Cm, float2 Kk, float2 Km,
                                          float cs, float sn, float2& Zk, float2& Zm) {
    float2 E  = make_float2(Ck.x + Cm.x, Ck.y - Cm.y);
    float2 O  = make_float2(Ck.x - Cm.x, Ck.y + Cm.y);
    float2 WO = make_float2(O.x*cs + O.y*sn, -O.x*sn + O.y*cs);
    float2 T  = make_float2(-WO.y, WO.x);
    float2 Uk = make_float2(0.5f*(E.x - T.x),  0.5f*(E.y - T.y));
    float2 Um = make_float2(0.5f*(E.x + T.x), -0.5f*(E.y + T.y));
    float2 Yk = cmul(Uk, Kk);
    float2 Ym = cmul(Um, Km);
    float2 P  = make_float2(Yk.x + Ym.x, Yk.y - Ym.y);
    float2 Q  = make_float2(Yk.x - Ym.x, Yk.y + Ym.y);
    float2 CQ = make_float2(Q.x*cs - Q.y*sn, Q.x*sn + Q.y*cs);
    float2 T2 = make_float2(-CQ.y, CQ.x);
    Zk = make_float2(P.x + T2.x, P.y + T2.y);
    Zm = make_float2(P.x - T2.x, -(P.y - T2.y));
}

// ---------------------------------------------------------------------------
// Kernel 1: implicit-filter MLP + out-projection + exponential modulation.
// grid (128,4): 64 positions x 256 channels per block.
// ---------------------------------------------------------------------------
__global__ void __launch_bounds__(256,2) hyena_filter_k(
    const float* __restrict__ W1, const float* __restrict__ b1,
    const float* __restrict__ freq,
    const float* __restrict__ W2, const float* __restrict__ b2,
    const float* __restrict__ W3, const float* __restrict__ b3,
    const float* __restrict__ Wout,
    float* __restrict__ kout)
{
    __shared__ float zbuf[64][35];   // (3p+e)%32 -> 2-way (free)
    __shared__ float abuf[64][66];   // stride 66: scalar reads 2-way free, rows 8B-aligned
    __shared__ float bbuf[64][66];
    __shared__ float wbuf[4352];     // weights (4096 floats); reused as obuf[256][17]

    const int tid = threadIdx.x;
    const int pbase = blockIdx.x * 64;

    for (int i = tid; i < 33*64; i += 256) wbuf[i] = W1[i];
    for (int idx = tid; idx < 64*33; idx += 256) {
        int p = idx & 63, e = idx >> 6;
        int gp = pbase + p;
        float w = 7.6699039394282907e-4f * (float)gp;   // 2*pi*gp/8192
        float val;
        if (e == 0)       val = (float)gp / 8191.0f;
        else if (e < 17)  val =  cosf((1.0e-4f + (float)(e-1 ) * ((15.0f-1.0e-4f)/15.0f)) * w);
        else              val = -sinf((1.0e-4f + (float)(e-17) * ((15.0f-1.0e-4f)/15.0f)) * w);
        zbuf[p][e] = val;
    }
    __syncthreads();

    const int p = tid & 63;
    const int g = tid >> 6;

    for (int oo = 0; oo < 16; ++oo) {
        int o = g*16 + oo;
        float acc = b1[o];
        #pragma unroll
        for (int e = 0; e < 33; ++e) acc += zbuf[p][e] * wbuf[e*64 + o];
        abuf[p][o] = __sinf(freq[o] * acc);
    }
    __syncthreads();
    for (int i = tid; i < 4096; i += 256) wbuf[i] = W2[i];
    __syncthreads();
    for (int oo = 0; oo < 16; ++oo) {
        int o = g*16 + oo;
        float acc = b2[o];
        #pragma unroll
        for (int e = 0; e < 64; ++e) acc += abuf[p][e] * wbuf[e*64 + o];
        bbuf[p][o] = __sinf(freq[o] * acc);
    }
    __syncthreads();
    for (int i = tid; i < 4096; i += 256) wbuf[i] = W3[i];
    __syncthreads();
    for (int oo = 0; oo < 16; ++oo) {
        int o = g*16 + oo;
        float acc = b3[o];
        #pragma unroll
        for (int e = 0; e < 64; ++e) acc += bbuf[p][e] * wbuf[e*64 + o];
        abuf[p][o] = __sinf(freq[o] * acc);
    }
    __syncthreads();

    // out-projection: channels-in-lanes, Wout column in registers, float2
    // broadcast activation reads, LDS-transposed coalesced writes.
    const int dd = blockIdx.y*256 + tid;
    float wreg[64];
    #pragma unroll
    for (int o = 0; o < 64; ++o) wreg[o] = Wout[o*1024 + dd];
    const float mind  = -3.0701134573253940f;
    const float dstep = -0.012004353694331942f;
    const float delta = fabsf(mind + dstep * (float)dd);
    const int lane = tid & 63, wv = tid >> 6;
    const int col = lane & 15, rsub = lane >> 4;

    for (int pc = 0; pc < 4; ++pc) {
        float res[16];
        #pragma unroll
        for (int pp = 0; pp < 16; ++pp) {
            int pq = pc*16 + pp;
            const float2* ar = (const float2*)&abuf[pq][0];
            float a0 = 0.f, a1 = 0.f;
            #pragma unroll
            for (int o2 = 0; o2 < 32; ++o2) {
                float2 av = ar[o2];
                a0 += av.x * wreg[2*o2];
                a1 += av.y * wreg[2*o2+1];
            }
            float t = (float)(pbase + pq) / 8191.0f;
            res[pp] = (a0 + a1) * __expf(-t * delta);
        }
        __syncthreads();   // prev obuf readers done (pc=0: weight readers done)
        #pragma unroll
        for (int pp = 0; pp < 16; ++pp) wbuf[tid*17 + pp] = res[pp];
        __syncthreads();
        #pragma unroll
        for (int it = 0; it < 16; ++it) {
            int row = wv*64 + it*4 + rsub;
            kout[(size_t)(blockIdx.y*256 + row)*LSEQ + pbase + pc*16 + col]
                = wbuf[row*17 + col];
        }
    }
}

// ---------------------------------------------------------------------------
// Kernel 2: per-channel FFT causal convolution + skip. One block per channel.
// Radix 8x8x8x16; pairing/multiply routed through LDS (low register pressure);
// filter spectrum in 64 persistent VGPRs; fused global I/O passes.
// ---------------------------------------------------------------------------
__global__ void __launch_bounds__(256,2) hyena_conv_k(
    const float* __restrict__ x, const float* kin,
    const float* __restrict__ Dvec, float* out)
{
    __shared__ float2 s[NC];                 // 64 KB
    const int tid = threadIdx.x;
    const int d = blockIdx.x;
    const float Dd = Dvec[d];
    const float invN = 1.0f / 16384.0f;

    // dft16-phase chunk assignment: thread handles chunks tid and tid+256
    const int bC0 = 16 * sig3(tid);
    const int bC1 = 16 * sig3(tid + 256);
    // pairing-phase bases (threads 1..255): chunks tid and 512-tid
    const int bT = bC0;
    const int bU = 16 * sig3((512 - tid) & 511);

    float2 Ka[16], Kb[16];

    // ---- filter FFT ----
    {
        const float2* kb = (const float2*)kin + (size_t)d * 4096;
        r8_fwd<1024,1>(s, kb, tid);
        __syncthreads();
        r8_fwd<128,0>(s, nullptr, tid);
        __syncthreads();
        r8_fwd<16,0>(s, nullptr, tid);
        __syncthreads();
        // M1: per-chunk dft16, spectrum back to LDS
        {
            float2 v[16];
            #pragma unroll
            for (int i = 0; i < 16; ++i) v[i] = s[sw(bC0 + i)];
            dft16<-1>(v);
            #pragma unroll
            for (int i = 0; i < 16; ++i) s[sw(bC0 + i)] = v[i];
        }
        {
            float2 v[16];
            #pragma unroll
            for (int i = 0; i < 16; ++i) v[i] = s[sw(bC1 + i)];
            dft16<-1>(v);
            #pragma unroll
            for (int i = 0; i < 16; ++i) s[sw(bC1 + i)] = v[i];
        }
        __syncthreads();
        // K extraction (read-only pairing): C[k]=chunk t idx v (k=t+512v)
        if (tid != 0) {
            #pragma unroll
            for (int v = 0; v < 16; ++v) {
                int k = tid + 512*v;
                float2 Ck = s[sw(bT + v)];
                float2 Cm = s[sw(bU + 15 - v)];
                float sn, cs; __sincosf(TWO_PI_OVER_N*(float)k, &sn, &cs);
                filt_pair(Ck, Cm, cs, sn, Ka[v], Kb[v]);
            }
        } else {
            float2 C0 = s[sw(0)];
            Ka[0] = make_float2((C0.x+C0.y)*invN, (C0.x-C0.y)*invN); // K[0],K[8192]
            float2 C4 = s[sw(8)];                                   // C[4096]
            Kb[0] = make_float2(C4.x*invN, -C4.y*invN);
            #pragma unroll
            for (int v = 1; v < 8; ++v) {
                int k = 512*v;
                float2 Ck = s[sw(v)], Cm = s[sw(16 - v)];
                float sn, cs; __sincosf(TWO_PI_OVER_N*(float)k, &sn, &cs);
                filt_pair(Ck, Cm, cs, sn, Ka[v], Kb[v]);
            }
            const int b256 = 16 * sig3(256);
            #pragma unroll
            for (int j = 0; j < 8; ++j) {
                int k = 256 + 512*j;
                float2 Ck = s[sw(b256 + j)], Cm = s[sw(b256 + 15 - j)];
                float sn, cs; __sincosf(TWO_PI_OVER_N*(float)k, &sn, &cs);
                filt_pair(Ck, Cm, cs, sn, Ka[8+j], Kb[8+j]);
            }
        }
    }

    // ---- per-batch conv ----
    for (int b = 0; b < 2; ++b) {
        __syncthreads();
        const float2* xv = (const float2*)x + ((size_t)b*D_MODEL + d) * 4096;
        float2* ov = (float2*)out + ((size_t)b*D_MODEL + d) * 4096;

        r8_fwd<1024,1>(s, xv, tid);
        __syncthreads();
        r8_fwd<128,0>(s, nullptr, tid);
        __syncthreads();
        r8_fwd<16,0>(s, nullptr, tid);
        __syncthreads();
        // M1: per-chunk dft16
        {
            float2 v[16];
            #pragma unroll
            for (int i = 0; i < 16; ++i) v[i] = s[sw(bC0 + i)];
            dft16<-1>(v);
            #pragma unroll
            for (int i = 0; i < 16; ++i) s[sw(bC0 + i)] = v[i];
        }
        {
            float2 v[16];
            #pragma unroll
            for (int i = 0; i < 16; ++i) v[i] = s[sw(bC1 + i)];
            dft16<-1>(v);
            #pragma unroll
            for (int i = 0; i < 16; ++i) s[sw(bC1 + i)] = v[i];
        }
        __syncthreads();
        // M2: pairing multiply in LDS
        if (tid != 0) {
            #pragma unroll
            for (int v = 0; v < 16; ++v) {
                int k = tid + 512*v;
                float2 Ck = s[sw(bT + v)];
                float2 Cm = s[sw(bU + 15 - v)];
                float sn, cs; __sincosf(TWO_PI_OVER_N*(float)k, &sn, &cs);
                float2 Zk, Zm;
                conv_pair(Ck, Cm, Ka[v], Kb[v], cs, sn, Zk, Zm);
                s[sw(bT + v)] = Zk;
                s[sw(bU + 15 - v)] = Zm;
            }
        } else {
            {
                float2 C0 = s[sw(0)];
                float U0 = C0.x + C0.y, UN = C0.x - C0.y;
                float Y0 = U0 * Ka[0].x, YN = UN * Ka[0].y;
                s[sw(0)] = make_float2(Y0 + YN, Y0 - YN);
                float2 C4 = s[sw(8)];
                float2 Uq = make_float2(C4.x, -C4.y);
                float2 Yq = cmul(Uq, Kb[0]);
                s[sw(8)] = make_float2(2.f*Yq.x, -2.f*Yq.y);
            }
            #pragma unroll
            for (int v = 1; v < 8; ++v) {
                int k = 512*v;
                float2 Ck = s[sw(v)], Cm = s[sw(16 - v)];
                float sn, cs; __sincosf(TWO_PI_OVER_N*(float)k, &sn, &cs);
                float2 Zk, Zm;
                conv_pair(Ck, Cm, Ka[v], Kb[v], cs, sn, Zk, Zm);
                s[sw(v)] = Zk; s[sw(16 - v)] = Zm;
            }
            const int b256 = 16 * sig3(256);
            #pragma unroll
            for (int j = 0; j < 8; ++j) {
                int k = 256 + 512*j;
                float2 Ck = s[sw(b256 + j)], Cm = s[sw(b256 + 15 - j)];
                float sn, cs; __sincosf(TWO_PI_OVER_N*(float)k, &sn, &cs);
                float2 Zk, Zm;
                conv_pair(Ck, Cm, Ka[8+j], Kb[8+j], cs, sn, Zk, Zm);
                s[sw(b256 + j)] = Zk; s[sw(b256 + 15 - j)] = Zm;
            }
        }
        __syncthreads();
        // M3: per-chunk idft16
        {
            float2 v[16];
            #pragma unroll
            for (int i = 0; i < 16; ++i) v[i] = s[sw(bC0 + i)];
            dft16<1>(v);
            #pragma unroll
            for (int i = 0; i < 16; ++i) s[sw(bC0 + i)] = v[i];
        }
        {
            float2 v[16];
            #pragma unroll
            for (int i = 0; i < 16; ++i) v[i] = s[sw(bC1 + i)];
            dft16<1>(v);
            #pragma unroll
            for (int i = 0; i < 16; ++i) s[sw(bC1 + i)] = v[i];
        }
        __syncthreads();
        r8_inv<16,0>(s, tid, nullptr, nullptr, 0.f);
        __syncthreads();
        r8_inv<128,0>(s, tid, nullptr, nullptr, 0.f);
        __syncthreads();
        r8_inv<1024,1>(s, tid, xv, ov, Dd);   // fused epilogue: y + x*D -> out
    }
}

extern "C" void kernel_launch(void* const* d_in, const int* in_sizes, int n_in,
                              void* d_out, int out_size, void* d_ws, size_t ws_size,
                              hipStream_t stream) {
    (void)in_sizes; (void)n_in; (void)out_size; (void)d_ws; (void)ws_size;
    const float* x    = (const float*)d_in[0];
    const float* W1   = (const float*)d_in[2];
    const float* b1   = (const float*)d_in[3];
    const float* freq = (const float*)d_in[4];
    const float* W2   = (const float*)d_in[5];
    const float* b2   = (const float*)d_in[6];
    const float* W3   = (const float*)d_in[7];
    const float* b3   = (const float*)d_in[8];
    const float* Wout = (const float*)d_in[9];
    const float* Dv   = (const float*)d_in[10];
    float* out = (float*)d_out;

    // Time-domain filter k[1024][8192] lives in the b=0 half of d_out:
    // conv block d is the sole reader of k[d] and sole later writer of out[0][d].
    float* kbuf = out;

    hipLaunchKernelGGL(hyena_filter_k, dim3(128, 4), dim3(256), 0, stream,
                       W1, b1, freq, W2, b2, W3, b3, Wout, kbuf);
    hipLaunchKernelGGL(hyena_conv_k, dim3(1024), dim3(256), 0, stream,
                       x, kbuf, Dv, out);
}

// Round 4
// 680.307 us; speedup vs baseline: 1.4223x; 1.3922x over previous
//
#include <hip/hip_runtime.h>

#define D_MODEL 1024
#define LSEQ    8192
#define NC      8192            // complex FFT size = (2*L)/2
#define TWO_PI_OVER_N 3.8349519697141029e-4f   // 2*pi/16384

// Double-XOR swizzle on LDS float2 index: keeps unit-stride wave patterns
// conflict-free and caps scattered chunk/pairing patterns at ~4-way.
__device__ __forceinline__ int sw(int e) { return e ^ ((e >> 4) & 15) ^ ((e >> 9) & 15); }
// base-8 3-digit reverse of a 9-bit chunk id
__device__ __forceinline__ int sig3(int c) { return ((c & 7) << 6) | (c & 56) | (c >> 6); }

__device__ __forceinline__ float2 cadd(float2 a, float2 b){ return make_float2(a.x+b.x, a.y+b.y); }
__device__ __forceinline__ float2 csub(float2 a, float2 b){ return make_float2(a.x-b.x, a.y-b.y); }
__device__ __forceinline__ float2 cmul(float2 a, float2 b){ return make_float2(a.x*b.x-a.y*b.y, a.x*b.y+a.y*b.x); }
template<int S> __device__ __forceinline__ float2 rot(float2 z){  // S=-1: -i*z ; S=+1: +i*z
    return (S < 0) ? make_float2(z.y, -z.x) : make_float2(-z.y, z.x);
}

// 8-point DFT, natural-order in/out. S=-1 forward, S=+1 unscaled inverse.
template<int S>
__device__ __forceinline__ void dft8(float2 v[8]) {
    const float c = 0.70710678118654752f;
    float2 a0=cadd(v[0],v[4]), m0=csub(v[0],v[4]);
    float2 a1=cadd(v[1],v[5]), m1=csub(v[1],v[5]);
    float2 a2=cadd(v[2],v[6]), m2=csub(v[2],v[6]);
    float2 a3=cadd(v[3],v[7]), m3=csub(v[3],v[7]);
    m1 = cmul(m1, make_float2(c, S*c));
    m2 = rot<S>(m2);
    m3 = cmul(m3, make_float2(-c, S*c));
    float2 b0=cadd(a0,a2), b2=csub(a0,a2);
    float2 b1=cadd(a1,a3), b3=rot<S>(csub(a1,a3));
    float2 e0=cadd(m0,m2), e2=csub(m0,m2);
    float2 e1=cadd(m1,m3), e3=rot<S>(csub(m1,m3));
    v[0]=cadd(b0,b1); v[4]=csub(b0,b1);
    v[2]=cadd(b2,b3); v[6]=csub(b2,b3);
    v[1]=cadd(e0,e1); v[5]=csub(e0,e1);
    v[3]=cadd(e2,e3); v[7]=csub(e2,e3);
}

// 16-point DFT, natural-order in/out (two radix-4 stages, constant twiddles).
template<int S>
__device__ __forceinline__ void dft16(float2 v[16]) {
    const float c  = 0.70710678118654752f;
    const float cp = 0.92387953251128676f;   // cos(pi/8)
    const float spp= 0.38268343236508977f;   // sin(pi/8)
    const float2 w1 = make_float2(cp,  S*spp);
    const float2 w2 = make_float2(c,   S*c);
    const float2 w3 = make_float2(spp, S*cp);
    const float2 w6 = make_float2(-c,  S*c);
    const float2 w9 = make_float2(-cp, -S*spp);
    float2 y[16];
    #pragma unroll
    for (int n=0;n<4;++n) {
        float2 s02=cadd(v[n],v[n+8]),  d02=csub(v[n],v[n+8]);
        float2 s13=cadd(v[n+4],v[n+12]), d13=csub(v[n+4],v[n+12]);
        float2 rd = rot<S>(d13);
        float2 F0=cadd(s02,s13), F2=csub(s02,s13);
        float2 F1=cadd(d02,rd),  F3=csub(d02,rd);
        y[n] = F0;
        if (n==0)      { y[4]=F1;            y[8]=F2;            y[12]=F3; }
        else if (n==1) { y[5]=cmul(F1,w1);   y[9]=cmul(F2,w2);   y[13]=cmul(F3,w3); }
        else if (n==2) { y[6]=cmul(F1,w2);   y[10]=rot<S>(F2);   y[14]=cmul(F3,w6); }
        else           { y[7]=cmul(F1,w3);   y[11]=cmul(F2,w6);  y[15]=cmul(F3,w9); }
    }
    #pragma unroll
    for (int r1=0;r1<4;++r1) {
        float2 q0=y[4*r1], q1=y[4*r1+1], q2=y[4*r1+2], q3=y[4*r1+3];
        float2 s02=cadd(q0,q2), d02=csub(q0,q2);
        float2 s13=cadd(q1,q3), d13=csub(q1,q3);
        float2 rd = rot<S>(d13);
        v[r1]    = cadd(s02,s13);
        v[4+r1]  = cadd(d02,rd);
        v[8+r1]  = csub(s02,s13);
        v[12+r1] = csub(d02,rd);
    }
}

// Radix-8 DIF pass, span H. FUSED=1: read legs from global (j<4), zero-pad j>=4.
template<int H, int FUSED>
__device__ __forceinline__ void r8_fwd(float2* s, const float2* gsrc, int tid) {
    const float ANG = -6.2831853071795865f / (8.0f * (float)H);
    #pragma unroll
    for (int t=0;t<4;++t) {
        int bf  = tid + t*256;
        int pos = bf & (H-1);
        int base = (bf - pos)*8 + pos;     // (bf/H)*8H + pos
        float2 v[8];
        if (FUSED) {
            #pragma unroll
            for (int j=0;j<4;++j) v[j] = gsrc[pos + j*1024];
            #pragma unroll
            for (int j=4;j<8;++j) v[j] = make_float2(0.f,0.f);
        } else {
            #pragma unroll
            for (int j=0;j<8;++j) v[j] = s[sw(base + j*H)];
        }
        dft8<-1>(v);
        float sn, cs; __sincosf(ANG * (float)pos, &sn, &cs);
        float2 w = make_float2(cs, sn), wr = w;
        v[1] = cmul(v[1], wr);
        #pragma unroll
        for (int r=2;r<8;++r) { wr = cmul(wr, w); v[r] = cmul(v[r], wr); }
        #pragma unroll
        for (int r=0;r<8;++r) s[sw(base + r*H)] = v[r];
    }
}

// Radix-8 DIT inverse pass, span H. EPI=1 (H=1024 only): fused epilogue
// out[e] = y[e] + x[e]*Dd for e<4096 (second half discarded), skip LDS write.
template<int H, int EPI>
__device__ __forceinline__ void r8_inv(float2* s, int tid, const float2* xg, float2* og, float Dd) {
    const float ANG = 6.2831853071795865f / (8.0f * (float)H);
    #pragma unroll
    for (int t=0;t<4;++t) {
        int bf  = tid + t*256;
        int pos = bf & (H-1);
        int base = (bf - pos)*8 + pos;
        float2 xr8[4];
        if (EPI) {
            #pragma unroll
            for (int j=0;j<4;++j) xr8[j] = xg[pos + j*1024];
        }
        float2 v[8];
        #pragma unroll
        for (int r=0;r<8;++r) v[r] = s[sw(base + r*H)];
        float sn, cs; __sincosf(ANG * (float)pos, &sn, &cs);
        float2 w = make_float2(cs, sn), wr = w;
        v[1] = cmul(v[1], wr);
        #pragma unroll
        for (int r=2;r<8;++r) { wr = cmul(wr, w); v[r] = cmul(v[r], wr); }
        dft8<1>(v);
        if (EPI) {
            #pragma unroll
            for (int j=0;j<4;++j) {
                og[pos + j*1024] = make_float2(v[j].x + xr8[j].x*Dd, v[j].y + xr8[j].y*Dd);
            }
        } else {
            #pragma unroll
            for (int j=0;j<8;++j) s[sw(base + j*H)] = v[j];
        }
    }
}

// Packed-real spectrum pair math (verified rounds 1-3).
__device__ __forceinline__ void filt_pair(float2 Ck, float2 Cm, float cs, float sn,
                                          float2& Kk, float2& Km) {
    const float hN = 0.5f / 16384.0f;
    float2 E  = make_float2(Ck.x + Cm.x, Ck.y - Cm.y);
    float2 O  = make_float2(Ck.x - Cm.x, Ck.y + Cm.y);
    float2 WO = make_float2(O.x*cs + O.y*sn, -O.x*sn + O.y*cs);
    float2 T  = make_float2(-WO.y, WO.x);
    Kk = make_float2((E.x - T.x)*hN,  (E.y - T.y)*hN);
    Km = make_float2((E.x + T.x)*hN, -(E.y + T.y)*hN);
}
__device__ __forceinline__ void conv_pair(float2 Ck, float2 Cm, float2 Kk, float2 Km,
                                          float cs, float sn, float2& Zk, float2& Zm) {
    float2 E  = make_float2(Ck.x + Cm.x, Ck.y - Cm.y);
    float2 O  = make_float2(Ck.x - Cm.x, Ck.y + Cm.y);
    float2 WO = make_float2(O.x*cs + O.y*sn, -O.x*sn + O.y*cs);
    float2 T  = make_float2(-WO.y, WO.x);
    float2 Uk = make_float2(0.5f*(E.x - T.x),  0.5f*(E.y - T.y));
    float2 Um = make_float2(0.5f*(E.x + T.x), -0.5f*(E.y + T.y));
    float2 Yk = cmul(Uk, Kk);
    float2 Ym = cmul(Um, Km);
    float2 P  = make_float2(Yk.x + Ym.x, Yk.y - Ym.y);
    float2 Q  = make_float2(Yk.x - Ym.x, Yk.y + Ym.y);
    float2 CQ = make_float2(Q.x*cs - Q.y*sn, Q.x*sn + Q.y*cs);
    float2 T2 = make_float2(-CQ.y, CQ.x);
    Zk = make_float2(P.x + T2.x, P.y + T2.y);
    Zm = make_float2(P.x - T2.x, -(P.y - T2.y));
}

// ---------------------------------------------------------------------------
// Kernel 1: implicit-filter MLP + out-projection + exponential modulation.
// grid (128,4): 64 positions x 256 channels per block.
// Embedding computed in registers; activations hoisted to registers per
// layer; weights read transposed as float4 broadcasts. NO ,2 launch bound:
// the 128-VGPR cap it induced caused scratch spill (R2/R3 post-mortem).
// ---------------------------------------------------------------------------
__global__ void __launch_bounds__(256) hyena_filter_k(
    const float* __restrict__ W1, const float* __restrict__ b1,
    const float* __restrict__ freq,
    const float* __restrict__ W2, const float* __restrict__ b2,
    const float* __restrict__ W3, const float* __restrict__ b3,
    const float* __restrict__ Wout,
    float* __restrict__ kout)
{
    __shared__ float abuf[64][66];   // stride 66: scalar reads 2-way free, rows 8B-aligned
    __shared__ float bbuf[64][66];
    __shared__ float wt[4352];       // transposed weights; reused as obuf[256][17]

    const int tid = threadIdx.x;
    const int pbase = blockIdx.x * 64;
    const int p = tid & 63;
    const int g = tid >> 6;
    const int o0 = g * 16;
    const int gp = pbase + p;

    // --- stage WT1[o][e] (stride 36, zero-padded e=33..35) ---
    for (int i = tid; i < 64*36; i += 256) wt[i] = 0.f;
    __syncthreads();
    for (int i = tid; i < 33*64; i += 256) wt[(i & 63)*36 + (i >> 6)] = W1[i];

    // --- positional embedding in registers ---
    float act[36];
    {
        float w = 7.6699039394282907e-4f * (float)gp;   // 2*pi*gp/8192
        act[0] = (float)gp / 8191.0f;
        #pragma unroll
        for (int j = 0; j < 16; ++j) {
            float f = 1.0e-4f + (float)j * ((15.0f - 1.0e-4f) / 15.0f);
            float sn, cs; __sincosf(f * w, &sn, &cs);
            act[1 + j]  = cs;
            act[17 + j] = -sn;
        }
        act[33] = 0.f; act[34] = 0.f; act[35] = 0.f;
    }
    __syncthreads();

    // --- layer 1: 33 -> 64 ---
    #pragma unroll 4
    for (int oo = 0; oo < 16; ++oo) {
        int o = o0 + oo;
        const float4* wr = (const float4*)&wt[o*36];
        float acc = b1[o];
        #pragma unroll
        for (int q = 0; q < 9; ++q) {
            float4 wv = wr[q];
            acc += act[4*q]*wv.x + act[4*q+1]*wv.y + act[4*q+2]*wv.z + act[4*q+3]*wv.w;
        }
        abuf[p][o] = __sinf(freq[o] * acc);
    }
    __syncthreads();

    // --- layer 2: 64 -> 64 ---
    for (int i = tid; i < 4096; i += 256) wt[(i & 63)*68 + (i >> 6)] = W2[i];
    float act2[64];
    #pragma unroll
    for (int e = 0; e < 64; ++e) act2[e] = abuf[p][e];
    __syncthreads();
    #pragma unroll 4
    for (int oo = 0; oo < 16; ++oo) {
        int o = o0 + oo;
        const float4* wr = (const float4*)&wt[o*68];
        float acc = b2[o];
        #pragma unroll
        for (int q = 0; q < 16; ++q) {
            float4 wv = wr[q];
            acc += act2[4*q]*wv.x + act2[4*q+1]*wv.y + act2[4*q+2]*wv.z + act2[4*q+3]*wv.w;
        }
        bbuf[p][o] = __sinf(freq[o] * acc);
    }
    __syncthreads();

    // --- layer 3: 64 -> 64 ---
    for (int i = tid; i < 4096; i += 256) wt[(i & 63)*68 + (i >> 6)] = W3[i];
    #pragma unroll
    for (int e = 0; e < 64; ++e) act2[e] = bbuf[p][e];
    __syncthreads();
    #pragma unroll 4
    for (int oo = 0; oo < 16; ++oo) {
        int o = o0 + oo;
        const float4* wr = (const float4*)&wt[o*68];
        float acc = b3[o];
        #pragma unroll
        for (int q = 0; q < 16; ++q) {
            float4 wv = wr[q];
            acc += act2[4*q]*wv.x + act2[4*q+1]*wv.y + act2[4*q+2]*wv.z + act2[4*q+3]*wv.w;
        }
        abuf[p][o] = __sinf(freq[o] * acc);
    }
    __syncthreads();

    // --- out-projection: channels-in-lanes, Wout column in registers, float2
    //     broadcast activation reads, LDS-transposed coalesced writes. ---
    const int dd = blockIdx.y*256 + tid;
    float wreg[64];
    #pragma unroll
    for (int o = 0; o < 64; ++o) wreg[o] = Wout[o*1024 + dd];
    const float mind  = -3.0701134573253940f;
    const float dstep = -0.012004353694331942f;
    const float delta = fabsf(mind + dstep * (float)dd);
    const int lane = tid & 63, wv = tid >> 6;
    const int col = lane & 15, rsub = lane >> 4;

    for (int pc = 0; pc < 4; ++pc) {
        float res[16];
        #pragma unroll
        for (int pp = 0; pp < 16; ++pp) {
            int pq = pc*16 + pp;
            const float2* ar = (const float2*)&abuf[pq][0];
            float a0 = 0.f, a1 = 0.f;
            #pragma unroll
            for (int o2 = 0; o2 < 32; ++o2) {
                float2 av = ar[o2];
                a0 += av.x * wreg[2*o2];
                a1 += av.y * wreg[2*o2+1];
            }
            float t = (float)(pbase + pq) / 8191.0f;
            res[pp] = (a0 + a1) * __expf(-t * delta);
        }
        __syncthreads();   // prev obuf readers done (pc=0: wt readers done)
        #pragma unroll
        for (int pp = 0; pp < 16; ++pp) wt[tid*17 + pp] = res[pp];
        __syncthreads();
        #pragma unroll
        for (int it = 0; it < 16; ++it) {
            int row = wv*64 + it*4 + rsub;
            kout[(size_t)(blockIdx.y*256 + row)*LSEQ + pbase + pc*16 + col]
                = wt[row*17 + col];
        }
    }
}

// ---------------------------------------------------------------------------
// Kernel 2: per-channel FFT causal convolution + skip. One block per channel.
// Radix 8x8x8x16; pairing routed through LDS; filter spectrum in 64 VGPRs.
// Plain __launch_bounds__(256): the (256,2) variant capped VGPRs at 128 and
// spilled ~1.6 GB to scratch (R2/R3). LDS (64 KB) bounds occupancy anyway.
// ---------------------------------------------------------------------------
__global__ void __launch_bounds__(256) hyena_conv_k(
    const float* __restrict__ x, const float* kin,
    const float* __restrict__ Dvec, float* out)
{
    __shared__ float2 s[NC];                 // 64 KB
    const int tid = threadIdx.x;
    const int d = blockIdx.x;
    const float Dd = Dvec[d];
    const float invN = 1.0f / 16384.0f;

    // dft16-phase chunk assignment: thread handles chunks tid and tid+256
    const int bC0 = 16 * sig3(tid);
    const int bC1 = 16 * sig3(tid + 256);
    // pairing-phase bases (threads 1..255): chunks tid and 512-tid
    const int bT = bC0;
    const int bU = 16 * sig3((512 - tid) & 511);

    float2 Ka[16], Kb[16];

    // ---- filter FFT ----
    {
        const float2* kb = (const float2*)kin + (size_t)d * 4096;
        r8_fwd<1024,1>(s, kb, tid);
        __syncthreads();
        r8_fwd<128,0>(s, nullptr, tid);
        __syncthreads();
        r8_fwd<16,0>(s, nullptr, tid);
        __syncthreads();
        // M1: per-chunk dft16, spectrum back to LDS
        {
            float2 v[16];
            #pragma unroll
            for (int i = 0; i < 16; ++i) v[i] = s[sw(bC0 + i)];
            dft16<-1>(v);
            #pragma unroll
            for (int i = 0; i < 16; ++i) s[sw(bC0 + i)] = v[i];
        }
        {
            float2 v[16];
            #pragma unroll
            for (int i = 0; i < 16; ++i) v[i] = s[sw(bC1 + i)];
            dft16<-1>(v);
            #pragma unroll
            for (int i = 0; i < 16; ++i) s[sw(bC1 + i)] = v[i];
        }
        __syncthreads();
        // K extraction (read-only pairing): C[k]=chunk t idx v (k=t+512v)
        if (tid != 0) {
            #pragma unroll
            for (int v = 0; v < 16; ++v) {
                int k = tid + 512*v;
                float2 Ck = s[sw(bT + v)];
                float2 Cm = s[sw(bU + 15 - v)];
                float sn, cs; __sincosf(TWO_PI_OVER_N*(float)k, &sn, &cs);
                filt_pair(Ck, Cm, cs, sn, Ka[v], Kb[v]);
            }
        } else {
            float2 C0 = s[sw(0)];
            Ka[0] = make_float2((C0.x+C0.y)*invN, (C0.x-C0.y)*invN); // K[0],K[8192]
            float2 C4 = s[sw(8)];                                   // C[4096]
            Kb[0] = make_float2(C4.x*invN, -C4.y*invN);
            #pragma unroll
            for (int v = 1; v < 8; ++v) {
                int k = 512*v;
                float2 Ck = s[sw(v)], Cm = s[sw(16 - v)];
                float sn, cs; __sincosf(TWO_PI_OVER_N*(float)k, &sn, &cs);
                filt_pair(Ck, Cm, cs, sn, Ka[v], Kb[v]);
            }
            const int b256 = 16 * sig3(256);
            #pragma unroll
            for (int j = 0; j < 8; ++j) {
                int k = 256 + 512*j;
                float2 Ck = s[sw(b256 + j)], Cm = s[sw(b256 + 15 - j)];
                float sn, cs; __sincosf(TWO_PI_OVER_N*(float)k, &sn, &cs);
                filt_pair(Ck, Cm, cs, sn, Ka[8+j], Kb[8+j]);
            }
        }
    }

    // ---- per-batch conv ----
    for (int b = 0; b < 2; ++b) {
        __syncthreads();
        const float2* xv = (const float2*)x + ((size_t)b*D_MODEL + d) * 4096;
        float2* ov = (float2*)out + ((size_t)b*D_MODEL + d) * 4096;

        r8_fwd<1024,1>(s, xv, tid);
        __syncthreads();
        r8_fwd<128,0>(s, nullptr, tid);
        __syncthreads();
        r8_fwd<16,0>(s, nullptr, tid);
        __syncthreads();
        // M1: per-chunk dft16
        {
            float2 v[16];
            #pragma unroll
            for (int i = 0; i < 16; ++i) v[i] = s[sw(bC0 + i)];
            dft16<-1>(v);
            #pragma unroll
            for (int i = 0; i < 16; ++i) s[sw(bC0 + i)] = v[i];
        }
        {
            float2 v[16];
            #pragma unroll
            for (int i = 0; i < 16; ++i) v[i] = s[sw(bC1 + i)];
            dft16<-1>(v);
            #pragma unroll
            for (int i = 0; i < 16; ++i) s[sw(bC1 + i)] = v[i];
        }
        __syncthreads();
        // M2: pairing multiply in LDS
        if (tid != 0) {
            #pragma unroll
            for (int v = 0; v < 16; ++v) {
                int k = tid + 512*v;
                float2 Ck = s[sw(bT + v)];
                float2 Cm = s[sw(bU + 15 - v)];
                float sn, cs; __sincosf(TWO_PI_OVER_N*(float)k, &sn, &cs);
                float2 Zk, Zm;
                conv_pair(Ck, Cm, Ka[v], Kb[v], cs, sn, Zk, Zm);
                s[sw(bT + v)] = Zk;
                s[sw(bU + 15 - v)] = Zm;
            }
        } else {
            {
                float2 C0 = s[sw(0)];
                float U0 = C0.x + C0.y, UN = C0.x - C0.y;
                float Y0 = U0 * Ka[0].x, YN = UN * Ka[0].y;
                s[sw(0)] = make_float2(Y0 + YN, Y0 - YN);
                float2 C4 = s[sw(8)];
                float2 Uq = make_float2(C4.x, -C4.y);
                float2 Yq = cmul(Uq, Kb[0]);
                s[sw(8)] = make_float2(2.f*Yq.x, -2.f*Yq.y);
            }
            #pragma unroll
            for (int v = 1; v < 8; ++v) {
                int k = 512*v;
                float2 Ck = s[sw(v)], Cm = s[sw(16 - v)];
                float sn, cs; __sincosf(TWO_PI_OVER_N*(float)k, &sn, &cs);
                float2 Zk, Zm;
                conv_pair(Ck, Cm, Ka[v], Kb[v], cs, sn, Zk, Zm);
                s[sw(v)] = Zk; s[sw(16 - v)] = Zm;
            }
            const int b256 = 16 * sig3(256);
            #pragma unroll
            for (int j = 0; j < 8; ++j) {
                int k = 256 + 512*j;
                float2 Ck = s[sw(b256 + j)], Cm = s[sw(b256 + 15 - j)];
                float sn, cs; __sincosf(TWO_PI_OVER_N*(float)k, &sn, &cs);
                float2 Zk, Zm;
                conv_pair(Ck, Cm, Ka[8+j], Kb[8+j], cs, sn, Zk, Zm);
                s[sw(b256 + j)] = Zk; s[sw(b256 + 15 - j)] = Zm;
            }
        }
        __syncthreads();
        // M3: per-chunk idft16
        {
            float2 v[16];
            #pragma unroll
            for (int i = 0; i < 16; ++i) v[i] = s[sw(bC0 + i)];
            dft16<1>(v);
            #pragma unroll
            for (int i = 0; i < 16; ++i) s[sw(bC0 + i)] = v[i];
        }
        {
            float2 v[16];
            #pragma unroll
            for (int i = 0; i < 16; ++i) v[i] = s[sw(bC1 + i)];
            dft16<1>(v);
            #pragma unroll
            for (int i = 0; i < 16; ++i) s[sw(bC1 + i)] = v[i];
        }
        __syncthreads();
        r8_inv<16,0>(s, tid, nullptr, nullptr, 0.f);
        __syncthreads();
        r8_inv<128,0>(s, tid, nullptr, nullptr, 0.f);
        __syncthreads();
        r8_inv<1024,1>(s, tid, xv, ov, Dd);   // fused epilogue: y + x*D -> out
    }
}

extern "C" void kernel_launch(void* const* d_in, const int* in_sizes, int n_in,
                              void* d_out, int out_size, void* d_ws, size_t ws_size,
                              hipStream_t stream) {
    (void)in_sizes; (void)n_in; (void)out_size; (void)d_ws; (void)ws_size;
    const float* x    = (const float*)d_in[0];
    const float* W1   = (const float*)d_in[2];
    const float* b1   = (const float*)d_in[3];
    const float* freq = (const float*)d_in[4];
    const float* W2   = (const float*)d_in[5];
    const float* b2   = (const float*)d_in[6];
    const float* W3   = (const float*)d_in[7];
    const float* b3   = (const float*)d_in[8];
    const float* Wout = (const float*)d_in[9];
    const float* Dv   = (const float*)d_in[10];
    float* out = (float*)d_out;

    // Time-domain filter k[1024][8192] lives in the b=0 half of d_out:
    // conv block d is the sole reader of k[d] and sole later writer of out[0][d].
    float* kbuf = out;

    hipLaunchKernelGGL(hyena_filter_k, dim3(128, 4), dim3(256), 0, stream,
                       W1, b1, freq, W2, b2, W3, b3, Wout, kbuf);
    hipLaunchKernelGGL(hyena_conv_k, dim3(1024), dim3(256), 0, stream,
                       x, kbuf, Dv, out);
}